// Round 1
// 554.578 us; speedup vs baseline: 1.0943x; 1.0943x over previous
//
#include <hip/hip_runtime.h>
#include <cstdint>
#include <cstddef>

// AdaptiveSparseSelfAttention — round 9: P2 top-64 selection probes moved off
// the VALU critical path. Count(>=cand) is now __ballot + __popcll (v_cmp ->
// s_bcnt1 on the SALU pipe) instead of per-lane adds + a 6-step shfl_xor
// reduce chain per probe; bounds scalarized via readfirstlane; prefix-bit walk
// replaced by an exact [min-lane-max, max] binary search (same semantics,
// early exit on cnt==64 unchanged). Per-wave numerics identical to R8
// (canary 0.00818).
//
// ws layout (68,157,440 B total):
//   Qf32 f32  [32][2048][64]                4,194,304 f  @ short 0
//   KF   bf16 [32][128 kt][3][2][64][8]    12,582,912 s  @ short 8,388,608
//   VF   bf16 [32][64 cc][4 dt][64][8]      4,194,304 s  @ short 20,971,520
//   HOS  bf16 [2 lev][8192][512]            8,388,608 s  @ short 25,165,824
//   WoS  bf16 [2 lev][512][512]               524,288 s  @ short 33,554,432

#define TSEQ 2048

typedef __attribute__((ext_vector_type(8))) short bf8;
typedef __attribute__((ext_vector_type(4))) float f32x4;

#define MFMA16(A, B, C) \
  C = __builtin_amdgcn_mfma_f32_16x16x32_bf16(A, B, C, 0, 0, 0)

static __device__ __forceinline__ short f2bf(float f) {
  unsigned u = __float_as_uint(f);
  u += 0x7FFFu + ((u >> 16) & 1u);
  return (short)(u >> 16);
}
static __device__ __forceinline__ float bf2f(short s) {
  return __uint_as_float(((unsigned)(unsigned short)s) << 16);
}

// ---------------------------------------- prep: transpose + split weight matrix
// W[K][N] -> out[lev][N][K], lev stride N*K
__global__ __launch_bounds__(256) void transpose_split(
    const float* __restrict__ W, short* __restrict__ out, int K, int N) {
  __shared__ float tile[32][129];
  const int t = threadIdx.x;
  const int nb = blockIdx.x * 128, kb = blockIdx.y * 32;
#pragma unroll
  for (int c = 0; c < 4; ++c) {
    const int flat = c * 256 + t;
    const int r = flat >> 5, nq = (flat & 31) * 4;
    const float4 g = *reinterpret_cast<const float4*>(&W[(size_t)(kb + r) * N + nb + nq]);
    tile[r][nq] = g.x; tile[r][nq + 1] = g.y;
    tile[r][nq + 2] = g.z; tile[r][nq + 3] = g.w;
  }
  __syncthreads();
  const int n = t >> 1, kh = (t & 1) * 16;
  bf8 a0, a1, b0, b1;
#pragma unroll
  for (int e = 0; e < 16; ++e) {
    const float f = tile[kh + e][n];
    const short s1 = f2bf(f);
    const short s2 = f2bf(f - bf2f(s1));
    if (e < 8) { a0[e] = s1; b0[e] = s2; }
    else       { a1[e - 8] = s1; b1[e - 8] = s2; }
  }
  const size_t o = (size_t)(nb + n) * K + kb + kh;
  const size_t ls = (size_t)N * K;
  *reinterpret_cast<bf8*>(out + o) = a0;
  *reinterpret_cast<bf8*>(out + o + 8) = a1;
  *reinterpret_cast<bf8*>(out + o + ls) = b0;
  *reinterpret_cast<bf8*>(out + o + ls + 8) = b1;
}

// ---------------------------------------------------------------- K1: qkv GEMM
// f32 VALU (R4-proven numerics). C[8192,1536] = X[8192,512] @ Wqkv[512,1536].
__global__ __launch_bounds__(256) void qkv_gemm(
    const float* __restrict__ X, const float* __restrict__ W,
    float* __restrict__ Qf32, short* __restrict__ KF, short* __restrict__ VF) {
  __shared__ float As[16][132];
  __shared__ float Bs[16][132];
  const int t = threadIdx.x;
  const int n0 = blockIdx.x * 128;
  const int m0 = blockIdx.y * 128;
  const int ti = t >> 4, tj = t & 15;
  float acc[8][8] = {};
  for (int kt = 0; kt < 512; kt += 16) {
#pragma unroll
    for (int e = 0; e < 2; ++e) {
      int idx = e * 256 + t;
      int m = idx >> 2, kq = (idx & 3) << 2;
      const float4 g = *reinterpret_cast<const float4*>(
          &X[(size_t)(m0 + m) * 512 + kt + kq]);
      As[kq + 0][m] = g.x; As[kq + 1][m] = g.y;
      As[kq + 2][m] = g.z; As[kq + 3][m] = g.w;
    }
#pragma unroll
    for (int e = 0; e < 2; ++e) {
      int idx = e * 256 + t;
      int kk = idx >> 5, n4 = (idx & 31) << 2;
      *reinterpret_cast<float4*>(&Bs[kk][n4]) =
          *reinterpret_cast<const float4*>(&W[(size_t)(kt + kk) * 1536 + n0 + n4]);
    }
    __syncthreads();
#pragma unroll
    for (int kk = 0; kk < 16; ++kk) {
      const float4 A0 = *reinterpret_cast<const float4*>(&As[kk][ti * 8]);
      const float4 A1 = *reinterpret_cast<const float4*>(&As[kk][ti * 8 + 4]);
      const float4 B0 = *reinterpret_cast<const float4*>(&Bs[kk][tj * 8]);
      const float4 B1 = *reinterpret_cast<const float4*>(&Bs[kk][tj * 8 + 4]);
      const float a[8] = {A0.x, A0.y, A0.z, A0.w, A1.x, A1.y, A1.z, A1.w};
      const float b[8] = {B0.x, B0.y, B0.z, B0.w, B1.x, B1.y, B1.z, B1.w};
#pragma unroll
      for (int ii = 0; ii < 8; ++ii)
#pragma unroll
        for (int jj = 0; jj < 8; ++jj)
          acc[ii][jj] = fmaf(a[ii], b[jj], acc[ii][jj]);
    }
    __syncthreads();
  }
  const int part = n0 >> 9;     // 0=Q 1=K 2=V
  if (part == 0) {
#pragma unroll
    for (int ii = 0; ii < 8; ++ii) {
      const int r = m0 + ti * 8 + ii;
      const int bb = r >> 11, tt = r & 2047;
#pragma unroll
      for (int jj = 0; jj < 8; ++jj) {
        const int c = (n0 & 511) + tj * 8 + jj;
        const int h = c >> 6, d = c & 63;
        Qf32[(size_t)(bb * 8 + h) * 131072 + (size_t)tt * 64 + d] =
            acc[ii][jj] * 0.125f;
      }
    }
  } else if (part == 1) {
    const int cc0 = (n0 & 511) + tj * 8;
    const int h = cc0 >> 6, d0 = cc0 & 63;
    const int kk = d0 >> 5, lg = (d0 & 31) >> 3;   // j = d&7 == jj
#pragma unroll
    for (int ii = 0; ii < 8; ++ii) {
      const int r = m0 + ti * 8 + ii;
      const int bb = r >> 11, tt = r & 2047;
      const size_t base = (size_t)(bb * 8 + h) * 393216 +
                          (size_t)(tt >> 4) * 3072 + kk * 512 +
                          ((tt & 15) + 16 * lg) * 8;
      bf8 v1, v2, v3;
#pragma unroll
      for (int jj = 0; jj < 8; ++jj) {
        const float f = acc[ii][jj];
        const short s1 = f2bf(f);  const float r1 = f - bf2f(s1);
        const short s2 = f2bf(r1);
        const short s3 = f2bf(r1 - bf2f(s2));
        v1[jj] = s1; v2[jj] = s2; v3[jj] = s3;
      }
      *reinterpret_cast<bf8*>(KF + base)        = v1;
      *reinterpret_cast<bf8*>(KF + base + 1024) = v2;
      *reinterpret_cast<bf8*>(KF + base + 2048) = v3;
    }
  } else {
    const int t0r = m0 + ti * 8;                 // 8-aligned -> j = s&7 == ii
    const int bb = t0r >> 11, tt0 = t0r & 2047;
    const int cc = tt0 >> 5, lgs = (tt0 & 31) >> 3;
#pragma unroll
    for (int jj = 0; jj < 8; ++jj) {
      const int c = (n0 & 511) + tj * 8 + jj;
      const int h = c >> 6, dd = c & 63;
      bf8 pv;
#pragma unroll
      for (int ii = 0; ii < 8; ++ii) pv[ii] = f2bf(acc[ii][jj]);
      *reinterpret_cast<bf8*>(VF + (size_t)(bb * 8 + h) * 131072 +
                              cc * 2048 + (dd >> 4) * 512 +
                              ((dd & 15) + 16 * lgs) * 8) = pv;
    }
  }
}

// ------------------------------------------------------------- K3: out proj GEMM
__global__ __launch_bounds__(256) void out_mfma(
    const short* __restrict__ HOS, const short* __restrict__ WoS,
    float* __restrict__ OUT) {
  __shared__ short As[2][128][40];
  __shared__ short Bs[2][128][40];
  const int t = threadIdx.x;
  const int w = t >> 6, lane = t & 63;
  const int lq = lane & 15, lg = lane >> 4;
  const int wr = w >> 1, wc = w & 1;
  const int n0 = blockIdx.x * 128, m0 = blockIdx.y * 128;
  f32x4 acc[4][4];
#pragma unroll
  for (int i = 0; i < 4; ++i)
#pragma unroll
    for (int j2 = 0; j2 < 4; ++j2) acc[i][j2] = (f32x4){0.f, 0.f, 0.f, 0.f};
  const int sm = t >> 1, sh = (t & 1) * 16;
  for (int k0 = 0; k0 < 512; k0 += 32) {
#pragma unroll
    for (int lev = 0; lev < 2; ++lev) {
      const size_t xa = (size_t)lev * 4194304 + (size_t)(m0 + sm) * 512 + k0 + sh;
      *reinterpret_cast<bf8*>(&As[lev][sm][sh])     = *reinterpret_cast<const bf8*>(HOS + xa);
      *reinterpret_cast<bf8*>(&As[lev][sm][sh + 8]) = *reinterpret_cast<const bf8*>(HOS + xa + 8);
      const size_t wa = (size_t)lev * 262144 + (size_t)(n0 + sm) * 512 + k0 + sh;
      *reinterpret_cast<bf8*>(&Bs[lev][sm][sh])     = *reinterpret_cast<const bf8*>(WoS + wa);
      *reinterpret_cast<bf8*>(&Bs[lev][sm][sh + 8]) = *reinterpret_cast<const bf8*>(WoS + wa + 8);
    }
    __syncthreads();
    bf8 af[4][2], bfr[4][2];
#pragma unroll
    for (int i = 0; i < 4; ++i)
#pragma unroll
      for (int lev = 0; lev < 2; ++lev) {
        af[i][lev]  = *reinterpret_cast<const bf8*>(&As[lev][wr * 64 + i * 16 + lq][lg * 8]);
        bfr[i][lev] = *reinterpret_cast<const bf8*>(&Bs[lev][wc * 64 + i * 16 + lq][lg * 8]);
      }
#pragma unroll
    for (int mi = 0; mi < 4; ++mi)
#pragma unroll
      for (int ni = 0; ni < 4; ++ni) {
        MFMA16(af[mi][0], bfr[ni][0], acc[mi][ni]);
        MFMA16(af[mi][0], bfr[ni][1], acc[mi][ni]);
        MFMA16(af[mi][1], bfr[ni][0], acc[mi][ni]);
      }
    __syncthreads();
  }
#pragma unroll
  for (int mi = 0; mi < 4; ++mi)
#pragma unroll
    for (int r = 0; r < 4; ++r) {
      const int m = m0 + wr * 64 + mi * 16 + lg * 4 + r;
#pragma unroll
      for (int ni = 0; ni < 4; ++ni)
        OUT[(size_t)m * 512 + n0 + wc * 64 + ni * 16 + lq] = acc[mi][ni][r];
    }
}

// ---------------------------------------------------------------- K2: attention
// 512 threads = 8 waves; 8 q-rows/block; 64 KB LDS -> 2 blocks/CU.
// Lanes lq>=8 duplicate rows 0-7 (row = lq&7): same-address/same-value LDS
// writes in P1, duplicate (discarded) MFMA rows in P3.
__global__ __launch_bounds__(512, 4) void attn_mfma(
    const float* __restrict__ Qf32, const short* __restrict__ KF,
    const short* __restrict__ VF, const float* __restrict__ alpha,
    short* __restrict__ HOS) {
  extern __shared__ char lds[];
  const int tid = threadIdx.x;
  const int w = tid >> 6, lane = tid & 63;      // w in [0,8)
  const int lq = lane & 15, lg = lane >> 4;
  const int row = lq & 7;

  // XCD swizzle: 8192 blocks, 1024/XCD = 4 bh x 256 qb
  const int flat = blockIdx.x + (int)gridDim.x * blockIdx.y;
  const int xcd = flat & 7, idx = flat >> 3;
  const int bh = xcd * 4 + (idx >> 8);
  const int qb = idx & 255;
  const int b = bh >> 3, h = bh & 7;
  const int q0 = qb * 8;

  const float gate = 1.0f / (1.0f + __expf(-alpha[h]));
  const int key = row;                           // row's swizzle key (row < 8)

  // Q fragments: load f32 row q0+row, split 3-level in-register
  bf8 qf[3][2];
  {
    const float* qp = Qf32 + (size_t)bh * 131072 + (size_t)(q0 + row) * 64 + lg * 8;
#pragma unroll
    for (int kk = 0; kk < 2; ++kk) {
      const float4 g0 = *reinterpret_cast<const float4*>(qp + kk * 32);
      const float4 g1 = *reinterpret_cast<const float4*>(qp + kk * 32 + 4);
      const float v[8] = {g0.x, g0.y, g0.z, g0.w, g1.x, g1.y, g1.z, g1.w};
#pragma unroll
      for (int e = 0; e < 8; ++e) {
        const short s1 = f2bf(v[e]);  const float r1 = v[e] - bf2f(s1);
        const short s2 = f2bf(r1);
        const short s3 = f2bf(r1 - bf2f(s2));
        qf[0][kk][e] = s1; qf[1][kk][e] = s2; qf[2][kk][e] = s3;
      }
    }
  }

  auto ldk = [&](int t, bf8 (&dst)[3][2]) {
    const short* p = KF + (size_t)(bh * 128 + t) * 3072 + lane * 8;
    dst[0][0] = *reinterpret_cast<const bf8*>(p);
    dst[0][1] = *reinterpret_cast<const bf8*>(p + 512);
    dst[1][0] = *reinterpret_cast<const bf8*>(p + 1024);
    dst[1][1] = *reinterpret_cast<const bf8*>(p + 1536);
    dst[2][0] = *reinterpret_cast<const bf8*>(p + 2048);
    dst[2][1] = *reinterpret_cast<const bf8*>(p + 2560);
  };
  auto qk = [&](bf8 (&kf)[3][2], int t) {
    f32x4 c0 = {0.f,0.f,0.f,0.f}, c1 = {0.f,0.f,0.f,0.f}, c2 = {0.f,0.f,0.f,0.f};
#pragma unroll
    for (int kk = 0; kk < 2; ++kk) {
      MFMA16(kf[0][kk], qf[0][kk], c0);   // 1
      MFMA16(kf[0][kk], qf[1][kk], c1);   // 2^-8
      MFMA16(kf[1][kk], qf[0][kk], c1);   // 2^-8
      MFMA16(kf[1][kk], qf[1][kk], c2);   // 2^-16
      MFMA16(kf[0][kk], qf[2][kk], c2);   // 2^-16
      MFMA16(kf[2][kk], qf[0][kk], c2);   // 2^-16
    }
    const f32x4 c = (c0 + c1) + c2;
    // lanes lq>=8 write the same address+value as their lq-8 twin (benign)
    *reinterpret_cast<f32x4*>(
        lds + row * 8192 + ((((t << 2) + lg) ^ key) << 4)) = c;
  };

  // ---- P1: logits (double-buffered, 16 tiles/wave)
  {
    bf8 ka[3][2], kb[3][2];
    ldk(w, ka);
#pragma unroll
    for (int j = 0; j < 16; j += 2) {
      const int t0 = w + 8 * j;
      ldk(t0 + 8, kb);
      qk(ka, t0);
      if (j + 2 < 16) ldk(t0 + 16, ka);
      qk(kb, t0 + 8);
    }
  }
  __syncthreads();

  // V prefetch for P3 chunk w (latency hidden under P2)
  bf8 va[4], vb[4];
  auto ldv = [&](int cc, bf8 (&dst)[4]) {
    const short* p = VF + (size_t)(bh * 64 + cc) * 2048 + lane * 8;
    dst[0] = *reinterpret_cast<const bf8*>(p);
    dst[1] = *reinterpret_cast<const bf8*>(p + 512);
    dst[2] = *reinterpret_cast<const bf8*>(p + 1024);
    dst[3] = *reinterpret_cast<const bf8*>(p + 1536);
  };
  ldv(w, va);

  // ---- P2: wave w owns row q=w. Exact top-64 threshold; counts via
  // ballot+popcount (SALU) instead of per-lane add + shfl reduce chains.
  {
    const int q = w;
    const int rkey = q & 7;
    const char* rowb = lds + q * 8192;
    unsigned uv[32];
    float lm = -3.402823466e+38f;
#pragma unroll
    for (int jj = 0; jj < 8; ++jj) {
      const f32x4 v = *reinterpret_cast<const f32x4*>(rowb + ((lane + 64 * jj) << 4));
#pragma unroll
      for (int e = 0; e < 4; ++e) {
        const float a = v[e];
        lm = fmaxf(lm, a);
        const unsigned fb = __float_as_uint(a);
        uv[jj * 4 + e] = (fb & 0x80000000u) ? ~fb : (fb | 0x80000000u);
      }
    }
    // m = global max; g0 = min of per-lane maxima -> cnt(>=g0) >= 64,
    // so the 64th-largest lies in [g0, m].
    float m = lm, g0 = lm;
#pragma unroll
    for (int off = 32; off; off >>= 1) m = fmaxf(m, __shfl_xor(m, off));
#pragma unroll
    for (int off = 32; off; off >>= 1) g0 = fminf(g0, __shfl_xor(g0, off));
    float ev[32]; float dsum = 0.f;
#pragma unroll
    for (int j = 0; j < 32; ++j) {
      const unsigned u = uv[j];
      const float a = __uint_as_float((u & 0x80000000u) ? (u & 0x7fffffffu) : ~u);
      ev[j] = __expf(a - m);
      dsum += ev[j];
    }
#pragma unroll
    for (int off = 32; off; off >>= 1) dsum += __shfl_xor(dsum, off);
    const unsigned um_ = __float_as_uint(m);
    const unsigned ug_ = __float_as_uint(g0);
    // scalarize bounds: loop control + candidates live entirely in SGPRs
    unsigned lo = __builtin_amdgcn_readfirstlane(
        (ug_ & 0x80000000u) ? ~ug_ : (ug_ | 0x80000000u));
    unsigned hi = __builtin_amdgcn_readfirstlane(
        (um_ & 0x80000000u) ? ~um_ : (um_ | 0x80000000u));
    // invariant: cnt(>= lo) >= 64. Find max T with cnt(>= T) >= 64.
    while (lo < hi) {
      const unsigned mid = lo + ((hi - lo + 1) >> 1);   // mid in (lo, hi]
      int cnt = 0;
#pragma unroll
      for (int j = 0; j < 32; ++j)
        cnt += (int)__popcll(__ballot(uv[j] >= mid));
      if (cnt >= 64) {
        lo = mid;
        if (cnt == 64) break;
      } else {
        hi = mid - 1;
      }
    }
    const unsigned thr = lo;
    float ssum = 0.f;
#pragma unroll
    for (int j = 0; j < 32; ++j) ssum += (uv[j] >= thr) ? ev[j] : 0.f;
#pragma unroll
    for (int off = 32; off; off >>= 1) ssum += __shfl_xor(ssum, off);
    const float dinv = gate / dsum;
    const float sinv = (1.0f - gate) / ssum;
#pragma unroll
    for (int jj = 0; jj < 8; ++jj) {
      const int p = lane + 64 * jj;
      const int f = p ^ rkey;
      const float w0 = ev[jj*4+0] * (dinv + ((uv[jj*4+0] >= thr) ? sinv : 0.f));
      const float w1 = ev[jj*4+1] * (dinv + ((uv[jj*4+1] >= thr) ? sinv : 0.f));
      const float w2 = ev[jj*4+2] * (dinv + ((uv[jj*4+2] >= thr) ? sinv : 0.f));
      const float w3 = ev[jj*4+3] * (dinv + ((uv[jj*4+3] >= thr) ? sinv : 0.f));
      uint2 pk;
      pk.x = (unsigned)(unsigned short)f2bf(w0) |
             ((unsigned)(unsigned short)f2bf(w1) << 16);
      pk.y = (unsigned)(unsigned short)f2bf(w2) |
             ((unsigned)(unsigned short)f2bf(w3) << 16);
      *reinterpret_cast<uint2*>(
          lds + q * 8192 + ((((f >> 1) ^ rkey) << 4) + ((f & 1) << 3))) = pk;
    }
  }
  __syncthreads();

  // ---- P3: PV. wave w does s-chunks cc = w + 8j (8 chunks of 32 s), 4 d-tiles.
  f32x4 o0 = {0.f,0.f,0.f,0.f}, o1 = {0.f,0.f,0.f,0.f};
  f32x4 o2 = {0.f,0.f,0.f,0.f}, o3 = {0.f,0.f,0.f,0.f};
  {
    auto pv = [&](bf8 (&vv)[4], int cc) {
      const bf8 pa = *reinterpret_cast<const bf8*>(
          lds + row * 8192 + ((((cc << 2) + lg) ^ key) << 4));
      MFMA16(pa, vv[0], o0);
      MFMA16(pa, vv[1], o1);
      MFMA16(pa, vv[2], o2);
      MFMA16(pa, vv[3], o3);
    };
#pragma unroll
    for (int j = 0; j < 8; j += 2) {
      const int cc = w + 8 * j;
      ldv(cc + 8, vb);
      pv(va, cc);
      if (j + 2 < 8) ldv(cc + 16, va);
      pv(vb, cc + 8);
    }
  }
  // park partials: tile = w*4+dt in [0,32): row tile&7, slot tile>>3
  {
    const f32x4 oo[4] = {o0, o1, o2, o3};
#pragma unroll
    for (int dt = 0; dt < 4; ++dt) {
      const int tile = w * 4 + dt;
      char* pb = lds + (tile & 7) * 8192 + 4096 + ((tile >> 3) << 10);
#pragma unroll
      for (int r = 0; r < 4; ++r)
        *reinterpret_cast<float*>(pb + (((lg * 4 + r) * 16 + lq) << 2)) = oo[dt][r];
    }
  }
  __syncthreads();
  // reduce 8 wave-partials, write HOS (2-level bf16). 512 thr = 8 q x 64 d.
  {
    const int q = tid >> 6, d = tid & 63;
    const int dt = d >> 4;
    float s = 0.f;
#pragma unroll
    for (int ww = 0; ww < 8; ++ww) {
      const int tile = ww * 4 + dt;
      s += *reinterpret_cast<const float*>(
          lds + (tile & 7) * 8192 + 4096 + ((tile >> 3) << 10) +
          ((q * 16 + (d & 15)) << 2));
    }
    const size_t o = (size_t)(b * TSEQ + q0 + q) * 512 + h * 64 + d;
    const short s1 = f2bf(s);
    HOS[o] = s1;
    HOS[o + 4194304] = f2bf(s - bf2f(s1));
  }
}

// ------------------------------------------------------------------- launcher
extern "C" void kernel_launch(void* const* d_in, const int* in_sizes, int n_in,
                              void* d_out, int out_size, void* d_ws, size_t ws_size,
                              hipStream_t stream) {
  const float* x     = (const float*)d_in[0];
  const float* Wqkv  = (const float*)d_in[1];
  const float* Wout  = (const float*)d_in[2];
  const float* alpha = (const float*)d_in[3];
  float* out = (float*)d_out;

  float* Qf32 = (float*)d_ws;
  short* S16  = (short*)d_ws;
  short* KF   = S16 + 8388608;
  short* VF   = S16 + 20971520;
  short* HOS  = S16 + 25165824;
  short* WoS  = S16 + 33554432;

  const int attn_lds = 65536;
  (void)hipFuncSetAttribute((const void*)attn_mfma,
                            hipFuncAttributeMaxDynamicSharedMemorySize, attn_lds);

  transpose_split<<<dim3(4, 16), 256, 0, stream>>>(Wout, WoS, 512, 512);
  qkv_gemm<<<dim3(12, 64), 256, 0, stream>>>(x, Wqkv, Qf32, KF, VF);
  attn_mfma<<<dim3(256, 32), 512, attn_lds, stream>>>(Qf32, KF, VF, alpha, HOS);
  out_mfma<<<dim3(4, 64), 256, 0, stream>>>(HOS, WoS, out);
}